// Round 2
// baseline (762.233 us; speedup 1.0000x reference)
//
#include <hip/hip_runtime.h>
#include <hip/hip_bf16.h>
#include <stdint.h>

#define L_ 2
#define N_ 100000
#define D_ 512
#define B_ 256
#define C_ 10
#define K_ 75
#define NCALI_ 750
#define CAP_ 4096       // per-row candidate capacity (expect ~820)
#define RCAP_ 1024      // rescore-set capacity (expect ~115)
#define TAUZ 2.4f       // pre-threshold in z units (true 75th at z~3.17)
#define MARGIN 0.06f    // >> 5-sigma bf16 dot error (~0.008)

typedef unsigned short u16;
typedef __attribute__((ext_vector_type(8))) short short8;
typedef __attribute__((ext_vector_type(4))) float f32x4;

// pack two floats into two rounded bf16s (lo in low 16 bits)
__device__ __forceinline__ unsigned pk_bf16(float lo, float hi) {
  unsigned a = __float_as_uint(lo) + 0x8000u;
  unsigned b = __float_as_uint(hi) + 0x8000u;
  return (a >> 16) | (b & 0xffff0000u);
}

// ---- query -> bf16, query norms, zero counters ----
__global__ __launch_bounds__(64) void k_qprep(const float* __restrict__ qf,
                                              u16* __restrict__ qb,
                                              float* __restrict__ qn,
                                              int* __restrict__ cnt,
                                              int* __restrict__ counts) {
  const int row  = blockIdx.x;      // 0..511 (l*256+b)
  const int lane = threadIdx.x;     // 0..63
  const float* src = qf + (size_t)row * D_ + lane * 8;
  float4 a = *(const float4*)(src);
  float4 b = *(const float4*)(src + 4);
  uint4 o;
  o.x = pk_bf16(a.x, a.y); o.y = pk_bf16(a.z, a.w);
  o.z = pk_bf16(b.x, b.y); o.w = pk_bf16(b.z, b.w);
  *(uint4*)(qb + (size_t)row * D_ + lane * 8) = o;
  float ss = a.x*a.x + a.y*a.y + a.z*a.z + a.w*a.w
           + b.x*b.x + b.y*b.y + b.z*b.z + b.w*b.w;
#pragma unroll
  for (int off = 32; off; off >>= 1) ss += __shfl_xor(ss, off);
  if (lane == 0) qn[row] = sqrtf(ss);
  if (row == 0) {
    for (int i = lane; i < L_ * B_; i += 64) cnt[i] = 0;
    for (int i = lane; i < B_ * C_; i += 64) counts[i] = 0;
  }
}

// ---- fused GEMM: score = (q . t) * rsqrt(||t||^2); append candidates >= tau ----
// BM=256 (all queries), BN=64, BK=64; 4 waves (2m x 2n); train read exactly once.
// A (query, bf16) read directly from global (L2-hot); B staged in XOR-swizzled LDS.
__global__ __launch_bounds__(256) void k_gemm(const float* __restrict__ tf,
                                              const u16* __restrict__ qb,
                                              const float* __restrict__ qn,
                                              int* __restrict__ cnt,
                                              uint2* __restrict__ pairs) {
  __shared__ __align__(16) u16 Bs[64 * 64];  // 8 KB, XOR-swizzled rows
  __shared__ float rnS[64];
  __shared__ float tauS[B_];
  const int tid   = threadIdx.x;
  const int layer = blockIdx.y;
  const int n0    = blockIdx.x * 64;
  const int lane  = tid & 63, wave = tid >> 6;
  const int wr    = wave >> 1, wc = wave & 1;
  const int kg    = lane >> 4, rl = lane & 15;

  const u16*   qbase = qb + (size_t)layer * B_ * D_;
  const float* tbase = tf + (size_t)layer * N_ * D_;

  // B-stage mapping: thread -> (row 0..63, 16-col segment 0..3)
  const int brow = tid >> 2, bseg = tid & 3;
  const int nb = n0 + brow;
  const int nc = nb < N_ ? nb : N_ - 1;
  const float* tsrc = tbase + (size_t)nc * D_ + bseg * 16;
  const int swb = (brow & 7) << 4;
  char* bsB = (char*)Bs + brow * 128;
  char* bd0 = bsB + ((bseg * 32) ^ swb);
  char* bd1 = bsB + ((bseg * 32 + 16) ^ swb);

  tauS[tid] = qn[layer * B_ + tid] * (TAUZ / 22.627416997969522f);

  f32x4 acc[8][2];
  const f32x4 vz = {0.f, 0.f, 0.f, 0.f};
#pragma unroll
  for (int i = 0; i < 8; ++i) { acc[i][0] = vz; acc[i][1] = vz; }
  float ss = 0.f;

  for (int kt = 0; kt < 8; ++kt) {
    const int k0 = kt * 64;
    __syncthreads();
    float4 f0 = *(const float4*)(tsrc + k0);
    float4 f1 = *(const float4*)(tsrc + k0 + 4);
    float4 f2 = *(const float4*)(tsrc + k0 + 8);
    float4 f3 = *(const float4*)(tsrc + k0 + 12);
    ss += f0.x*f0.x + f0.y*f0.y + f0.z*f0.z + f0.w*f0.w
        + f1.x*f1.x + f1.y*f1.y + f1.z*f1.z + f1.w*f1.w
        + f2.x*f2.x + f2.y*f2.y + f2.z*f2.z + f2.w*f2.w
        + f3.x*f3.x + f3.y*f3.y + f3.z*f3.z + f3.w*f3.w;
    uint4 o0, o1;
    o0.x = pk_bf16(f0.x, f0.y); o0.y = pk_bf16(f0.z, f0.w);
    o0.z = pk_bf16(f1.x, f1.y); o0.w = pk_bf16(f1.z, f1.w);
    o1.x = pk_bf16(f2.x, f2.y); o1.y = pk_bf16(f2.z, f2.w);
    o1.z = pk_bf16(f3.x, f3.y); o1.w = pk_bf16(f3.z, f3.w);
    *(uint4*)bd0 = o0;
    *(uint4*)bd1 = o1;
    __syncthreads();
#pragma unroll
    for (int ks = 0; ks < 2; ++ks) {
      short8 bfr[2];
#pragma unroll
      for (int nf = 0; nf < 2; ++nf) {
        const int r = wc * 32 + nf * 16 + rl;
        bfr[nf] = *(const short8*)((const char*)Bs + r * 128 +
                                   ((ks * 64 + kg * 16) ^ ((r & 7) << 4)));
      }
      const u16* aK = qbase + (size_t)(wr * 128 + rl) * D_ + k0 + ks * 32 + kg * 8;
#pragma unroll
      for (int mf = 0; mf < 8; ++mf) {
        const short8 a = *(const short8*)(aK + (size_t)mf * 16 * D_);
        acc[mf][0] = __builtin_amdgcn_mfma_f32_16x16x32_bf16(a, bfr[0], acc[mf][0], 0, 0, 0);
        acc[mf][1] = __builtin_amdgcn_mfma_f32_16x16x32_bf16(a, bfr[1], acc[mf][1], 0, 0, 0);
      }
    }
  }
  // full-row ||t||^2 (4 threads per row hold quarters)
  ss += __shfl_xor(ss, 1);
  ss += __shfl_xor(ss, 2);
  if ((tid & 3) == 0) rnS[brow] = 1.0f / sqrtf(ss);
  __syncthreads();

  const int crow = (lane >> 4) * 4;
  int*   cntL   = cnt + layer * B_;
  uint2* pairsL = pairs + (size_t)layer * B_ * CAP_;
#pragma unroll
  for (int nf = 0; nf < 2; ++nf) {
    const int cidx = wc * 32 + nf * 16 + rl;
    const int n = n0 + cidx;
    if (n < N_) {
      const float rn = rnS[cidx];
#pragma unroll
      for (int mf = 0; mf < 8; ++mf) {
        const int bq0 = wr * 128 + mf * 16 + crow;
#pragma unroll
        for (int j = 0; j < 4; ++j) {
          const float s = acc[mf][nf][j] * rn;
          const int bq = bq0 + j;
          if (s >= tauS[bq]) {
            const int pos = atomicAdd(&cntL[bq], 1);
            if (pos < CAP_)
              pairsL[(size_t)bq * CAP_ + pos] = make_uint2(__float_as_uint(s), (unsigned)n);
          }
        }
      }
    }
  }
}

// ---- per-(layer,query): rank-75 threshold among candidates -> fp64 rescore -> exact rank ----
__global__ __launch_bounds__(256) void k_select(const uint2* __restrict__ pairs,
                                                const int* __restrict__ cnt,
                                                const float* __restrict__ tf,
                                                const float* __restrict__ qf,
                                                const int* __restrict__ labels,
                                                int* __restrict__ counts) {
  __shared__ float  sVal[CAP_];
  __shared__ int    sIdx[CAP_];
  __shared__ int    rIdxN[RCAP_];
  __shared__ double rVal[RCAP_];
  __shared__ unsigned s75u;
  __shared__ int nRs;
  const int tid   = threadIdx.x;
  const int b     = blockIdx.x;
  const int layer = blockIdx.y;
  const int m = min(cnt[layer * B_ + b], CAP_);
  const uint2* pb = pairs + ((size_t)layer * B_ + b) * CAP_;
  for (int i = tid; i < m; i += 256) {
    uint2 p = pb[i];
    sVal[i] = __uint_as_float(p.x);
    sIdx[i] = (int)p.y;
  }
  if (tid == 0) { s75u = 0u; nRs = 0; }
  __syncthreads();

  // exact 75th-largest approx score (total order: value desc, idx asc)
  if (m > K_) {
    for (int c = tid; c < m; c += 256) {
      const float vc = sVal[c];
      const int   ic = sIdx[c];
      int r = 0;
      for (int j = 0; j < m; ++j) {
        const float vj = sVal[j];
        r += (vj > vc) || (vj == vc && sIdx[j] < ic);
      }
      if (r == K_ - 1) s75u = __float_as_uint(vc);   // unique writer
    }
  }
  __syncthreads();
  const float tr = (m > K_) ? (__uint_as_float(s75u) - MARGIN) : -1e30f;
  for (int c = tid; c < m; c += 256) {
    if (sVal[c] >= tr) {
      const int p = atomicAdd(&nRs, 1);
      if (p < RCAP_) rIdxN[p] = sIdx[c];
    }
  }
  __syncthreads();
  const int R = min(nRs, RCAP_);

  // exact fp64 rescore: one wave per candidate row
  const int lane = tid & 63, wave = tid >> 6;
  const float* q     = qf + ((size_t)layer * B_ + b) * D_;
  const float* tbase = tf + (size_t)layer * N_ * D_;
  const float4 qa = *(const float4*)(q + lane * 8);
  const float4 qc = *(const float4*)(q + lane * 8 + 4);
  for (int c = wave; c < R; c += 4) {
    const float* t = tbase + (size_t)rIdxN[c] * D_ + lane * 8;
    const float4 ta = *(const float4*)t;
    const float4 tc = *(const float4*)(t + 4);
    double dot = (double)qa.x * ta.x + (double)qa.y * ta.y
               + (double)qa.z * ta.z + (double)qa.w * ta.w
               + (double)qc.x * tc.x + (double)qc.y * tc.y
               + (double)qc.z * tc.z + (double)qc.w * tc.w;
    double sq  = (double)ta.x * ta.x + (double)ta.y * ta.y
               + (double)ta.z * ta.z + (double)ta.w * ta.w
               + (double)tc.x * tc.x + (double)tc.y * tc.y
               + (double)tc.z * tc.z + (double)tc.w * tc.w;
#pragma unroll
    for (int off = 32; off; off >>= 1) {
      dot += __shfl_xor(dot, off);
      sq  += __shfl_xor(sq, off);
    }
    if (lane == 0) rVal[c] = dot / sqrt(sq);
  }
  __syncthreads();

  // exact rank among rescored set (contains all true top-75)
  for (int c = tid; c < R; c += 256) {
    const double vc = rVal[c];
    const int    ic = rIdxN[c];
    int r = 0;
    for (int j = 0; j < R; ++j) {
      const double vj = rVal[j];
      r += (vj > vc) || (vj == vc && rIdxN[j] < ic);
    }
    if (r < K_) atomicAdd(&counts[b * C_ + labels[ic]], 1);
  }
}

// ---- conformal p-values + credibility ----
__global__ __launch_bounds__(1024) void k_final(const int* __restrict__ counts,
                                                const int* __restrict__ cali,
                                                float* __restrict__ out) {
  __shared__ int   cal[NCALI_];
  __shared__ float pv[B_ * C_];
  const int tid = threadIdx.x;
  for (int i = tid; i < NCALI_; i += 1024) cal[i] = cali[i];
  __syncthreads();
  for (int t = tid; t < B_ * C_; t += 1024) {
    const int val = L_ * K_ - counts[t];
    int cntv = 0;
    for (int i = 0; i < NCALI_; ++i) cntv += (cal[i] >= val) ? 1 : 0;
    pv[t] = (float)cntv / (float)NCALI_;
  }
  __syncthreads();
  for (int b = tid; b < B_; b += 1024) {
    float best = pv[b * C_];
    int bc = 0;
#pragma unroll
    for (int c = 1; c < C_; ++c) {
      const float p = pv[b * C_ + c];
      if (p > best) { best = p; bc = c; }
    }
#pragma unroll
    for (int c = 0; c < C_; ++c) out[b * C_ + c] = (c == bc) ? best : 0.f;
  }
}

extern "C" void kernel_launch(void* const* d_in, const int* in_sizes, int n_in,
                              void* d_out, int out_size, void* d_ws, size_t ws_size,
                              hipStream_t stream) {
  (void)in_sizes; (void)n_in; (void)out_size;
  const float* train  = (const float*)d_in[0];
  const float* query  = (const float*)d_in[1];
  const int*   labels = (const int*)d_in[2];
  const int*   cali   = (const int*)d_in[3];
  float* out = (float*)d_out;

  char* ws = (char*)d_ws;
  u16*   qb     = (u16*)  (ws);             //    524,288 B [L*B*D bf16]
  float* qn     = (float*)(ws + 524288);    //      2,048 B [L*B]
  int*   cnt    = (int*)  (ws + 526336);    //      2,048 B [L*B]
  int*   counts = (int*)  (ws + 528384);    //     10,240 B [B*C]
  uint2* pairs  = (uint2*)(ws + 538624);    // 16,777,216 B [L*B*CAP_]
  if (ws_size < 17315840u) return;

  k_qprep<<<dim3(L_ * B_), dim3(64), 0, stream>>>(query, qb, qn, cnt, counts);
  k_gemm<<<dim3((N_ + 63) / 64, L_), dim3(256), 0, stream>>>(train, qb, qn, cnt, pairs);
  k_select<<<dim3(B_, L_), dim3(256), 0, stream>>>(pairs, cnt, train, query, labels, counts);
  k_final<<<dim3(1), dim3(1024), 0, stream>>>(counts, cali, out);
}

// Round 3
// 659.795 us; speedup vs baseline: 1.1553x; 1.1553x over previous
//
#include <hip/hip_runtime.h>
#include <hip/hip_bf16.h>
#include <stdint.h>

#define L_ 2
#define N_ 100000
#define D_ 512
#define B_ 256
#define C_ 10
#define K_ 75
#define NCALI_ 750
#define CAP_ 4096       // per-row candidate capacity (expect ~820)
#define RCAP_ 1024      // rescore-set capacity (expect ~115)
#define TAUZ 2.4f       // pre-threshold in z units (true 75th at z~3.17)
#define MARGIN 0.06f    // >> 5-sigma bf16 dot error (~0.008)
#define BN_ 128

typedef unsigned short u16;
typedef __attribute__((ext_vector_type(8))) short short8;
typedef __attribute__((ext_vector_type(4))) float f32x4;

// pack two floats into two rounded bf16s (lo in low 16 bits)
__device__ __forceinline__ unsigned pk_bf16(float lo, float hi) {
  unsigned a = __float_as_uint(lo) + 0x8000u;
  unsigned b = __float_as_uint(hi) + 0x8000u;
  return (a >> 16) | (b & 0xffff0000u);
}

#define GLOAD_LDS16(g, l)                                          \
  __builtin_amdgcn_global_load_lds(                                \
      (const __attribute__((address_space(1))) void*)(g),          \
      (__attribute__((address_space(3))) void*)(l), 16, 0, 0)

// ---- query -> bf16 PRE-SWIZZLED layout, query norms, zero counters ----
// qb layout: [l][kt 0..7][row 0..255][slot 0..7][8 bf16], slot = c8 ^ (row&7)
__global__ __launch_bounds__(64) void k_qprep(const float* __restrict__ qf,
                                              u16* __restrict__ qb,
                                              float* __restrict__ qn,
                                              int* __restrict__ cnt,
                                              int* __restrict__ counts) {
  const int row  = blockIdx.x;      // 0..511 (l*256+b)
  const int l    = row >> 8, b = row & 255;
  const int lane = threadIdx.x;     // 0..63
  const int kt = lane >> 3, c8 = lane & 7;
  const float* src = qf + (size_t)row * D_ + lane * 8;
  float4 a = *(const float4*)(src);
  float4 bv = *(const float4*)(src + 4);
  uint4 o;
  o.x = pk_bf16(a.x, a.y);  o.y = pk_bf16(a.z, a.w);
  o.z = pk_bf16(bv.x, bv.y); o.w = pk_bf16(bv.z, bv.w);
  const int slot = c8 ^ (b & 7);
  *(uint4*)(qb + (size_t)l * B_ * D_ + ((kt * 256 + b) * 8 + slot) * 8) = o;
  float ss = a.x*a.x + a.y*a.y + a.z*a.z + a.w*a.w
           + bv.x*bv.x + bv.y*bv.y + bv.z*bv.z + bv.w*bv.w;
#pragma unroll
  for (int off = 32; off; off >>= 1) ss += __shfl_xor(ss, off);
  if (lane == 0) qn[row] = sqrtf(ss);
  if (row == 0) {
    for (int i = lane; i < L_ * B_; i += 64) cnt[i] = 0;
    for (int i = lane; i < B_ * C_; i += 64) counts[i] = 0;
  }
}

// ---- fused GEMM: score = (q . t) * rsqrt(||t||^2); append candidates >= tau ----
// BM=256 (all queries), BN=128, BK=64; 8 waves (2m x 4n); train read exactly once.
// A staged via global_load_lds from pre-swizzled qb; B reg-staged fp32->bf16 swizzled.
__global__ __launch_bounds__(512) void k_gemm(const float* __restrict__ tf,
                                              const u16* __restrict__ qb,
                                              const float* __restrict__ qn,
                                              int* __restrict__ cnt,
                                              uint2* __restrict__ pairs) {
  __shared__ __align__(16) u16 As[256 * 64];   // 32 KB, swizzled
  __shared__ __align__(16) u16 Bs[BN_ * 64];   // 16 KB, swizzled
  __shared__ float rnS[BN_];
  __shared__ float tauS[B_];
  const int tid   = threadIdx.x;               // 0..511
  const int layer = blockIdx.y;
  const int n0    = blockIdx.x * BN_;
  const int lane  = tid & 63, wave = tid >> 6; // 8 waves
  const int wr    = wave >> 2, wc = wave & 3;  // 2 M-halves x 4 N-quarters
  const int kg    = lane >> 4, rl = lane & 15;

  const u16*   qbase = qb + (size_t)layer * B_ * D_;
  const float* tbase = tf + (size_t)layer * N_ * D_;

  // B staging: thread -> (row 0..127, seg 0..3 of 16 cols)
  const int brow = tid >> 2, bseg = tid & 3;
  const int nb = n0 + brow;
  const int nc = nb < N_ ? nb : N_ - 1;
  const float* tsrc = tbase + (size_t)nc * D_ + bseg * 16;
  const int sw = brow & 7;
  char* bsB = (char*)Bs + brow * 128;
  char* bd0 = bsB + (((bseg * 2)     ^ sw) << 4);
  char* bd1 = bsB + (((bseg * 2 + 1) ^ sw) << 4);

  if (tid < B_) tauS[tid] = qn[layer * B_ + tid] * (TAUZ / 22.627416997969522f);

  f32x4 acc[8][2];
  const f32x4 vz = {0.f, 0.f, 0.f, 0.f};
#pragma unroll
  for (int i = 0; i < 8; ++i) { acc[i][0] = vz; acc[i][1] = vz; }
  float ss = 0.f;

  for (int kt = 0; kt < 8; ++kt) {
    const float* ts = tsrc + kt * 64;
    float4 f0 = *(const float4*)(ts);
    float4 f1 = *(const float4*)(ts + 4);
    float4 f2 = *(const float4*)(ts + 8);
    float4 f3 = *(const float4*)(ts + 12);
    __syncthreads();   // previous tile fully consumed
    // A stage: 32 KB slab, linear DMA (layout already swizzled in global)
    {
      const char* aslab = (const char*)(qbase + kt * 16384);
      char* adst = (char*)As;
#pragma unroll
      for (int i = 0; i < 4; ++i) {
        const int c = i * 8 + wave;           // 1 KB chunk per wave-issue
        GLOAD_LDS16(aslab + c * 1024 + lane * 16, adst + c * 1024);
      }
    }
    // B stage: convert + swizzled ds_write, accumulate ||t||^2
    ss += f0.x*f0.x + f0.y*f0.y + f0.z*f0.z + f0.w*f0.w
        + f1.x*f1.x + f1.y*f1.y + f1.z*f1.z + f1.w*f1.w
        + f2.x*f2.x + f2.y*f2.y + f2.z*f2.z + f2.w*f2.w
        + f3.x*f3.x + f3.y*f3.y + f3.z*f3.z + f3.w*f3.w;
    uint4 o0, o1;
    o0.x = pk_bf16(f0.x, f0.y); o0.y = pk_bf16(f0.z, f0.w);
    o0.z = pk_bf16(f1.x, f1.y); o0.w = pk_bf16(f1.z, f1.w);
    o1.x = pk_bf16(f2.x, f2.y); o1.y = pk_bf16(f2.z, f2.w);
    o1.z = pk_bf16(f3.x, f3.y); o1.w = pk_bf16(f3.z, f3.w);
    *(uint4*)bd0 = o0;
    *(uint4*)bd1 = o1;
    __syncthreads();   // drains vmcnt (DMA) + lgkm (ds_write)
#pragma unroll
    for (int ks = 0; ks < 2; ++ks) {
      const int g = ks * 4 + kg;               // 8-elem k-granule index
      short8 bfr[2];
#pragma unroll
      for (int nf = 0; nf < 2; ++nf) {
        const int r = wc * 32 + nf * 16 + rl;
        bfr[nf] = *(const short8*)((const char*)Bs + r * 128 + ((g ^ (r & 7)) << 4));
      }
#pragma unroll
      for (int mf = 0; mf < 8; ++mf) {
        const int m = wr * 128 + mf * 16 + rl;
        const short8 a = *(const short8*)((const char*)As + m * 128 + ((g ^ (m & 7)) << 4));
        acc[mf][0] = __builtin_amdgcn_mfma_f32_16x16x32_bf16(a, bfr[0], acc[mf][0], 0, 0, 0);
        acc[mf][1] = __builtin_amdgcn_mfma_f32_16x16x32_bf16(a, bfr[1], acc[mf][1], 0, 0, 0);
      }
    }
  }
  // full-row ||t||^2 (4 threads per row hold quarters)
  ss += __shfl_xor(ss, 1);
  ss += __shfl_xor(ss, 2);
  if ((tid & 3) == 0) rnS[brow] = 1.0f / sqrtf(ss);
  __syncthreads();

  const int crow = (lane >> 4) * 4;
  int*   cntL   = cnt + layer * B_;
  uint2* pairsL = pairs + (size_t)layer * B_ * CAP_;
#pragma unroll
  for (int nf = 0; nf < 2; ++nf) {
    const int cidx = wc * 32 + nf * 16 + rl;
    const int n = n0 + cidx;
    if (n < N_) {
      const float rn = rnS[cidx];
#pragma unroll
      for (int mf = 0; mf < 8; ++mf) {
        const int bq0 = wr * 128 + mf * 16 + crow;
#pragma unroll
        for (int j = 0; j < 4; ++j) {
          const float s = acc[mf][nf][j] * rn;
          const int bq = bq0 + j;
          if (s >= tauS[bq]) {
            const int pos = atomicAdd(&cntL[bq], 1);
            if (pos < CAP_)
              pairsL[(size_t)bq * CAP_ + pos] = make_uint2(__float_as_uint(s), (unsigned)n);
          }
        }
      }
    }
  }
}

// ---- per-(layer,query): rank-75 threshold among candidates -> fp64 rescore -> exact rank ----
__global__ __launch_bounds__(256) void k_select(const uint2* __restrict__ pairs,
                                                const int* __restrict__ cnt,
                                                const float* __restrict__ tf,
                                                const float* __restrict__ qf,
                                                const int* __restrict__ labels,
                                                int* __restrict__ counts) {
  __shared__ float  sVal[CAP_];
  __shared__ int    sIdx[CAP_];
  __shared__ int    rIdxN[RCAP_];
  __shared__ double rVal[RCAP_];
  __shared__ unsigned s75u;
  __shared__ int nRs;
  const int tid   = threadIdx.x;
  const int b     = blockIdx.x;
  const int layer = blockIdx.y;
  const int m = min(cnt[layer * B_ + b], CAP_);
  const uint2* pb = pairs + ((size_t)layer * B_ + b) * CAP_;
  for (int i = tid; i < m; i += 256) {
    uint2 p = pb[i];
    sVal[i] = __uint_as_float(p.x);
    sIdx[i] = (int)p.y;
  }
  if (tid == 0) { s75u = 0u; nRs = 0; }
  __syncthreads();

  // exact 75th-largest approx score (total order: value desc, idx asc)
  if (m > K_) {
    for (int c = tid; c < m; c += 256) {
      const float vc = sVal[c];
      const int   ic = sIdx[c];
      int r = 0;
      for (int j = 0; j < m; ++j) {
        const float vj = sVal[j];
        r += (vj > vc) || (vj == vc && sIdx[j] < ic);
      }
      if (r == K_ - 1) s75u = __float_as_uint(vc);   // unique writer
    }
  }
  __syncthreads();
  const float tr = (m > K_) ? (__uint_as_float(s75u) - MARGIN) : -1e30f;
  for (int c = tid; c < m; c += 256) {
    if (sVal[c] >= tr) {
      const int p = atomicAdd(&nRs, 1);
      if (p < RCAP_) rIdxN[p] = sIdx[c];
    }
  }
  __syncthreads();
  const int R = min(nRs, RCAP_);

  // exact fp64 rescore: one wave per candidate row
  const int lane = tid & 63, wave = tid >> 6;
  const float* q     = qf + ((size_t)layer * B_ + b) * D_;
  const float* tbase = tf + (size_t)layer * N_ * D_;
  const float4 qa = *(const float4*)(q + lane * 8);
  const float4 qc = *(const float4*)(q + lane * 8 + 4);
  for (int c = wave; c < R; c += 4) {
    const float* t = tbase + (size_t)rIdxN[c] * D_ + lane * 8;
    const float4 ta = *(const float4*)t;
    const float4 tc = *(const float4*)(t + 4);
    double dot = (double)qa.x * ta.x + (double)qa.y * ta.y
               + (double)qa.z * ta.z + (double)qa.w * ta.w
               + (double)qc.x * tc.x + (double)qc.y * tc.y
               + (double)qc.z * tc.z + (double)qc.w * tc.w;
    double sq  = (double)ta.x * ta.x + (double)ta.y * ta.y
               + (double)ta.z * ta.z + (double)ta.w * ta.w
               + (double)tc.x * tc.x + (double)tc.y * tc.y
               + (double)tc.z * tc.z + (double)tc.w * tc.w;
#pragma unroll
    for (int off = 32; off; off >>= 1) {
      dot += __shfl_xor(dot, off);
      sq  += __shfl_xor(sq, off);
    }
    if (lane == 0) rVal[c] = dot / sqrt(sq);
  }
  __syncthreads();

  // exact rank among rescored set (contains all true top-75)
  for (int c = tid; c < R; c += 256) {
    const double vc = rVal[c];
    const int    ic = rIdxN[c];
    int r = 0;
    for (int j = 0; j < R; ++j) {
      const double vj = rVal[j];
      r += (vj > vc) || (vj == vc && rIdxN[j] < ic);
    }
    if (r < K_) atomicAdd(&counts[b * C_ + labels[ic]], 1);
  }
}

// ---- conformal p-values + credibility ----
__global__ __launch_bounds__(1024) void k_final(const int* __restrict__ counts,
                                                const int* __restrict__ cali,
                                                float* __restrict__ out) {
  __shared__ int   cal[NCALI_];
  __shared__ float pv[B_ * C_];
  const int tid = threadIdx.x;
  for (int i = tid; i < NCALI_; i += 1024) cal[i] = cali[i];
  __syncthreads();
  for (int t = tid; t < B_ * C_; t += 1024) {
    const int val = L_ * K_ - counts[t];
    int cntv = 0;
    for (int i = 0; i < NCALI_; ++i) cntv += (cal[i] >= val) ? 1 : 0;
    pv[t] = (float)cntv / (float)NCALI_;
  }
  __syncthreads();
  for (int b = tid; b < B_; b += 1024) {
    float best = pv[b * C_];
    int bc = 0;
#pragma unroll
    for (int c = 1; c < C_; ++c) {
      const float p = pv[b * C_ + c];
      if (p > best) { best = p; bc = c; }
    }
#pragma unroll
    for (int c = 0; c < C_; ++c) out[b * C_ + c] = (c == bc) ? best : 0.f;
  }
}

extern "C" void kernel_launch(void* const* d_in, const int* in_sizes, int n_in,
                              void* d_out, int out_size, void* d_ws, size_t ws_size,
                              hipStream_t stream) {
  (void)in_sizes; (void)n_in; (void)out_size;
  const float* train  = (const float*)d_in[0];
  const float* query  = (const float*)d_in[1];
  const int*   labels = (const int*)d_in[2];
  const int*   cali   = (const int*)d_in[3];
  float* out = (float*)d_out;

  char* ws = (char*)d_ws;
  u16*   qb     = (u16*)  (ws);             //    524,288 B [L*B*D bf16, swizzled]
  float* qn     = (float*)(ws + 524288);    //      2,048 B [L*B]
  int*   cnt    = (int*)  (ws + 526336);    //      2,048 B [L*B]
  int*   counts = (int*)  (ws + 528384);    //     10,240 B [B*C]
  uint2* pairs  = (uint2*)(ws + 538624);    // 16,777,216 B [L*B*CAP_]
  if (ws_size < 17315840u) return;

  k_qprep<<<dim3(L_ * B_), dim3(64), 0, stream>>>(query, qb, qn, cnt, counts);
  k_gemm<<<dim3((N_ + BN_ - 1) / BN_, L_), dim3(512), 0, stream>>>(train, qb, qn, cnt, pairs);
  k_select<<<dim3(B_, L_), dim3(256), 0, stream>>>(pairs, cnt, train, query, labels, counts);
  k_final<<<dim3(1), dim3(1024), 0, stream>>>(counts, cali, out);
}

// Round 4
// 635.843 us; speedup vs baseline: 1.1988x; 1.0377x over previous
//
#include <hip/hip_runtime.h>
#include <hip/hip_bf16.h>
#include <stdint.h>

#define L_ 2
#define N_ 100000
#define D_ 512
#define B_ 256
#define C_ 10
#define K_ 75
#define NCALI_ 750
#define CAP_ 4096       // per-row candidate capacity (expect ~820)
#define RCAP_ 1024      // rescore-set capacity (expect ~115)
#define TAUZ 2.4f       // pre-threshold in z units (true 75th at z~3.17)
#define MARGIN 0.06f    // >> 5-sigma bf16 dot error (~0.008)
#define BN_ 64

typedef unsigned short u16;
typedef __attribute__((ext_vector_type(8))) short short8;
typedef __attribute__((ext_vector_type(4))) float f32x4;

// pack two floats into two rounded bf16s (lo in low 16 bits)
__device__ __forceinline__ unsigned pk_bf16(float lo, float hi) {
  unsigned a = __float_as_uint(lo) + 0x8000u;
  unsigned b = __float_as_uint(hi) + 0x8000u;
  return (a >> 16) | (b & 0xffff0000u);
}

// ---- query -> bf16 (linear), query norms, zero counters ----
__global__ __launch_bounds__(64) void k_qprep(const float* __restrict__ qf,
                                              u16* __restrict__ qb,
                                              float* __restrict__ qn,
                                              int* __restrict__ cnt,
                                              int* __restrict__ counts) {
  const int row  = blockIdx.x;      // 0..511 (l*256+b)
  const int lane = threadIdx.x;     // 0..63
  const float* src = qf + (size_t)row * D_ + lane * 8;
  float4 a = *(const float4*)(src);
  float4 b = *(const float4*)(src + 4);
  uint4 o;
  o.x = pk_bf16(a.x, a.y); o.y = pk_bf16(a.z, a.w);
  o.z = pk_bf16(b.x, b.y); o.w = pk_bf16(b.z, b.w);
  *(uint4*)(qb + (size_t)row * D_ + lane * 8) = o;
  float ss = a.x*a.x + a.y*a.y + a.z*a.z + a.w*a.w
           + b.x*b.x + b.y*b.y + b.z*b.z + b.w*b.w;
#pragma unroll
  for (int off = 32; off; off >>= 1) ss += __shfl_xor(ss, off);
  if (lane == 0) qn[row] = sqrtf(ss);
  if (row == 0) {
    for (int i = lane; i < L_ * B_; i += 64) cnt[i] = 0;
    for (int i = lane; i < B_ * C_; i += 64) counts[i] = 0;
  }
}

// ---- fused GEMM: score = (q . t) * rsqrt(||t||^2); append candidates >= tau ----
// BM=256 (all queries), BN=64, BK=64; 4 waves (2m x 2n); 256 threads; train read once.
// Chunk-interleaved staging: every wave-instr reads lane-consecutive 16B chunks.
__global__ __launch_bounds__(256) void k_gemm(const float* __restrict__ tf,
                                              const u16* __restrict__ qb,
                                              const float* __restrict__ qn,
                                              int* __restrict__ cnt,
                                              uint2* __restrict__ pairs) {
  __shared__ __align__(16) u16 As[256 * 64];   // 32 KB, XOR-swizzled
  __shared__ __align__(16) u16 Bs[BN_ * 64];   //  8 KB, XOR-swizzled
  __shared__ float rnS[BN_];
  __shared__ float tauS[B_];
  const int tid   = threadIdx.x;               // 0..255
  const int layer = blockIdx.y;
  const int n0    = blockIdx.x * BN_;
  const int lane  = tid & 63, wave = tid >> 6; // 4 waves
  const int wr    = wave >> 1, wc = wave & 1;  // 2 M-halves x 2 N-halves
  const int kg    = lane >> 4, rl = lane & 15;

  const u16*   qbase = qb + (size_t)layer * B_ * D_;
  const float* tbase = tf + (size_t)layer * N_ * D_;

  tauS[tid] = qn[layer * B_ + tid] * (TAUZ / 22.627416997969522f);

  // A staging: 8 chunks/thread; chunk j -> row = j*32 + (tid>>3), c16 = tid&7
  const int arow0 = tid >> 3, ac16 = tid & 7;
  // B staging: 4 chunks/thread; chunk j -> row = j*16 + (tid>>4), c16 = tid&15
  const int brow0 = tid >> 4, bc16 = tid & 15;

  float ssj[4] = {0.f, 0.f, 0.f, 0.f};
  f32x4 acc[8][2];
  const f32x4 vz = {0.f, 0.f, 0.f, 0.f};
#pragma unroll
  for (int i = 0; i < 8; ++i) { acc[i][0] = vz; acc[i][1] = vz; }

  for (int kt = 0; kt < 8; ++kt) {
    // B global loads (fp32), coalesced: 4 rows x 256B contiguous per wave-instr
    float4 bf[4];
#pragma unroll
    for (int j = 0; j < 4; ++j) {
      int row = j * 16 + brow0;
      int n = n0 + row; n = n < N_ ? n : N_ - 1;
      bf[j] = *(const float4*)(tbase + (size_t)n * D_ + kt * 64 + bc16 * 4);
    }
    __syncthreads();   // previous tile fully consumed
    // A stage: 8 rows x 128B contiguous per wave-instr; swizzled ds_write_b128
#pragma unroll
    for (int j = 0; j < 8; ++j) {
      const int row = j * 32 + arow0;
      uint4 v = *(const uint4*)(qbase + (size_t)row * D_ + kt * 64 + ac16 * 8);
      *(uint4*)((char*)As + row * 128 + ((ac16 ^ (row & 7)) << 4)) = v;
    }
    // B stage: convert + swizzled ds_write_b64, accumulate ||t||^2 per chunk-row
#pragma unroll
    for (int j = 0; j < 4; ++j) {
      const int row = j * 16 + brow0;
      const float4 f = bf[j];
      ssj[j] += f.x*f.x + f.y*f.y + f.z*f.z + f.w*f.w;
      uint2 o;
      o.x = pk_bf16(f.x, f.y);
      o.y = pk_bf16(f.z, f.w);
      *(uint2*)((char*)Bs + row * 128 + ((((bc16 >> 1)) ^ (row & 7)) << 4) + (bc16 & 1) * 8) = o;
    }
    __syncthreads();   // tile ready
#pragma unroll
    for (int ks = 0; ks < 2; ++ks) {
      const int g = ks * 4 + kg;               // 8-elem k-granule index
      short8 bfr[2];
#pragma unroll
      for (int nf = 0; nf < 2; ++nf) {
        const int r = wc * 32 + nf * 16 + rl;
        bfr[nf] = *(const short8*)((const char*)Bs + r * 128 + ((g ^ (r & 7)) << 4));
      }
#pragma unroll
      for (int mf = 0; mf < 8; ++mf) {
        const int m = wr * 128 + mf * 16 + rl;
        const short8 a = *(const short8*)((const char*)As + m * 128 + ((g ^ (m & 7)) << 4));
        acc[mf][0] = __builtin_amdgcn_mfma_f32_16x16x32_bf16(a, bfr[0], acc[mf][0], 0, 0, 0);
        acc[mf][1] = __builtin_amdgcn_mfma_f32_16x16x32_bf16(a, bfr[1], acc[mf][1], 0, 0, 0);
      }
    }
  }
  // full-row 1/||t||: reduce ssj within 16-lane chunk groups
#pragma unroll
  for (int j = 0; j < 4; ++j) {
    float s = ssj[j];
    s += __shfl_xor(s, 1);
    s += __shfl_xor(s, 2);
    s += __shfl_xor(s, 4);
    s += __shfl_xor(s, 8);
    if ((lane & 15) == 0) rnS[j * 16 + wave * 4 + (lane >> 4)] = 1.0f / sqrtf(s);
  }
  __syncthreads();

  const int crow = (lane >> 4) * 4;
  int*   cntL   = cnt + layer * B_;
  uint2* pairsL = pairs + (size_t)layer * B_ * CAP_;
#pragma unroll
  for (int nf = 0; nf < 2; ++nf) {
    const int cidx = wc * 32 + nf * 16 + rl;
    const int n = n0 + cidx;
    if (n < N_) {
      const float rn = rnS[cidx];
#pragma unroll
      for (int mf = 0; mf < 8; ++mf) {
        const int bq0 = wr * 128 + mf * 16 + crow;
#pragma unroll
        for (int j = 0; j < 4; ++j) {
          const float s = acc[mf][nf][j] * rn;
          const int bq = bq0 + j;
          if (s >= tauS[bq]) {
            const int pos = atomicAdd(&cntL[bq], 1);
            if (pos < CAP_)
              pairsL[(size_t)bq * CAP_ + pos] = make_uint2(__float_as_uint(s), (unsigned)n);
          }
        }
      }
    }
  }
}

// ---- per-(layer,query): rank-75 threshold among candidates -> fp64 rescore -> exact rank ----
__global__ __launch_bounds__(256) void k_select(const uint2* __restrict__ pairs,
                                                const int* __restrict__ cnt,
                                                const float* __restrict__ tf,
                                                const float* __restrict__ qf,
                                                const int* __restrict__ labels,
                                                int* __restrict__ counts) {
  __shared__ float  sVal[CAP_];
  __shared__ int    sIdx[CAP_];
  __shared__ int    rIdxN[RCAP_];
  __shared__ double rVal[RCAP_];
  __shared__ unsigned s75u;
  __shared__ int nRs;
  const int tid   = threadIdx.x;
  const int b     = blockIdx.x;
  const int layer = blockIdx.y;
  const int m = min(cnt[layer * B_ + b], CAP_);
  const uint2* pb = pairs + ((size_t)layer * B_ + b) * CAP_;
  for (int i = tid; i < m; i += 256) {
    uint2 p = pb[i];
    sVal[i] = __uint_as_float(p.x);
    sIdx[i] = (int)p.y;
  }
  if (tid == 0) { s75u = 0u; nRs = 0; }
  __syncthreads();

  // exact 75th-largest approx score (total order: value desc, idx asc)
  if (m > K_) {
    for (int c = tid; c < m; c += 256) {
      const float vc = sVal[c];
      const int   ic = sIdx[c];
      int r = 0;
      for (int j = 0; j < m; ++j) {
        const float vj = sVal[j];
        r += (vj > vc) || (vj == vc && sIdx[j] < ic);
      }
      if (r == K_ - 1) s75u = __float_as_uint(vc);   // unique writer
    }
  }
  __syncthreads();
  const float tr = (m > K_) ? (__uint_as_float(s75u) - MARGIN) : -1e30f;
  for (int c = tid; c < m; c += 256) {
    if (sVal[c] >= tr) {
      const int p = atomicAdd(&nRs, 1);
      if (p < RCAP_) rIdxN[p] = sIdx[c];
    }
  }
  __syncthreads();
  const int R = min(nRs, RCAP_);

  // exact fp64 rescore: one wave per candidate row
  const int lane = tid & 63, wave = tid >> 6;
  const float* q     = qf + ((size_t)layer * B_ + b) * D_;
  const float* tbase = tf + (size_t)layer * N_ * D_;
  const float4 qa = *(const float4*)(q + lane * 8);
  const float4 qc = *(const float4*)(q + lane * 8 + 4);
  for (int c = wave; c < R; c += 4) {
    const float* t = tbase + (size_t)rIdxN[c] * D_ + lane * 8;
    const float4 ta = *(const float4*)t;
    const float4 tc = *(const float4*)(t + 4);
    double dot = (double)qa.x * ta.x + (double)qa.y * ta.y
               + (double)qa.z * ta.z + (double)qa.w * ta.w
               + (double)qc.x * tc.x + (double)qc.y * tc.y
               + (double)qc.z * tc.z + (double)qc.w * tc.w;
    double sq  = (double)ta.x * ta.x + (double)ta.y * ta.y
               + (double)ta.z * ta.z + (double)ta.w * ta.w
               + (double)tc.x * tc.x + (double)tc.y * tc.y
               + (double)tc.z * tc.z + (double)tc.w * tc.w;
#pragma unroll
    for (int off = 32; off; off >>= 1) {
      dot += __shfl_xor(dot, off);
      sq  += __shfl_xor(sq, off);
    }
    if (lane == 0) rVal[c] = dot / sqrt(sq);
  }
  __syncthreads();

  // exact rank among rescored set (contains all true top-75)
  for (int c = tid; c < R; c += 256) {
    const double vc = rVal[c];
    const int    ic = rIdxN[c];
    int r = 0;
    for (int j = 0; j < R; ++j) {
      const double vj = rVal[j];
      r += (vj > vc) || (vj == vc && rIdxN[j] < ic);
    }
    if (r < K_) atomicAdd(&counts[b * C_ + labels[ic]], 1);
  }
}

// ---- conformal p-values + credibility ----
__global__ __launch_bounds__(1024) void k_final(const int* __restrict__ counts,
                                                const int* __restrict__ cali,
                                                float* __restrict__ out) {
  __shared__ int   cal[NCALI_];
  __shared__ float pv[B_ * C_];
  const int tid = threadIdx.x;
  for (int i = tid; i < NCALI_; i += 1024) cal[i] = cali[i];
  __syncthreads();
  for (int t = tid; t < B_ * C_; t += 1024) {
    const int val = L_ * K_ - counts[t];
    int cntv = 0;
    for (int i = 0; i < NCALI_; ++i) cntv += (cal[i] >= val) ? 1 : 0;
    pv[t] = (float)cntv / (float)NCALI_;
  }
  __syncthreads();
  for (int b = tid; b < B_; b += 1024) {
    float best = pv[b * C_];
    int bc = 0;
#pragma unroll
    for (int c = 1; c < C_; ++c) {
      const float p = pv[b * C_ + c];
      if (p > best) { best = p; bc = c; }
    }
#pragma unroll
    for (int c = 0; c < C_; ++c) out[b * C_ + c] = (c == bc) ? best : 0.f;
  }
}

extern "C" void kernel_launch(void* const* d_in, const int* in_sizes, int n_in,
                              void* d_out, int out_size, void* d_ws, size_t ws_size,
                              hipStream_t stream) {
  (void)in_sizes; (void)n_in; (void)out_size;
  const float* train  = (const float*)d_in[0];
  const float* query  = (const float*)d_in[1];
  const int*   labels = (const int*)d_in[2];
  const int*   cali   = (const int*)d_in[3];
  float* out = (float*)d_out;

  char* ws = (char*)d_ws;
  u16*   qb     = (u16*)  (ws);             //    524,288 B [L*B*D bf16]
  float* qn     = (float*)(ws + 524288);    //      2,048 B [L*B]
  int*   cnt    = (int*)  (ws + 526336);    //      2,048 B [L*B]
  int*   counts = (int*)  (ws + 528384);    //     10,240 B [B*C]
  uint2* pairs  = (uint2*)(ws + 538624);    // 16,777,216 B [L*B*CAP_]
  if (ws_size < 17315840u) return;

  k_qprep<<<dim3(L_ * B_), dim3(64), 0, stream>>>(query, qb, qn, cnt, counts);
  k_gemm<<<dim3((N_ + BN_ - 1) / BN_, L_), dim3(256), 0, stream>>>(train, qb, qn, cnt, pairs);
  k_select<<<dim3(B_, L_), dim3(256), 0, stream>>>(pairs, cnt, train, query, labels, counts);
  k_final<<<dim3(1), dim3(1024), 0, stream>>>(counts, cali, out);
}

// Round 5
// 338.208 us; speedup vs baseline: 2.2537x; 1.8800x over previous
//
#include <hip/hip_runtime.h>
#include <hip/hip_bf16.h>
#include <stdint.h>

#define L_ 2
#define N_ 100000
#define D_ 512
#define B_ 256
#define C_ 10
#define K_ 75
#define NCALI_ 750
#define CAP_ 4096       // per-row candidate capacity in k_select (expect ~820)
#define RCAP_ 1024      // rescore-set capacity (expect ~115)
#define TAUZ 2.4f       // pre-threshold in z units (true 75th at z~3.17)
#define MARGIN 0.06f    // >> 5-sigma bf16 dot error (~0.008)
#define BN_ 64
#define NBX_ 1563       // (N_+63)/64
#define SLOTS_ 4        // slots per (query, block) cell
#define OVF_CAP 65536

typedef unsigned short u16;
typedef __attribute__((ext_vector_type(8))) short short8;
typedef __attribute__((ext_vector_type(4))) float f32x4;

// pack two floats into two rounded bf16s (lo in low 16 bits)
__device__ __forceinline__ unsigned pk_bf16(float lo, float hi) {
  unsigned a = __float_as_uint(lo) + 0x8000u;
  unsigned b = __float_as_uint(hi) + 0x8000u;
  return (a >> 16) | (b & 0xffff0000u);
}

// ---- zero the slot slab + overflow counter (every call: replay determinism) ----
__global__ __launch_bounds__(256) void k_zero(uint4* __restrict__ p, long n16,
                                              unsigned* __restrict__ ovfCnt) {
  long i = (long)blockIdx.x * 256 + threadIdx.x;
  const long stride = (long)gridDim.x * 256;
  const uint4 z = {0u, 0u, 0u, 0u};
  for (; i < n16; i += stride) p[i] = z;
  if (blockIdx.x == 0 && threadIdx.x == 0) *ovfCnt = 0u;
}

// ---- query -> bf16 (linear), query norms, zero class counts ----
__global__ __launch_bounds__(64) void k_qprep(const float* __restrict__ qf,
                                              u16* __restrict__ qb,
                                              float* __restrict__ qn,
                                              int* __restrict__ counts) {
  const int row  = blockIdx.x;      // 0..511 (l*256+b)
  const int lane = threadIdx.x;     // 0..63
  const float* src = qf + (size_t)row * D_ + lane * 8;
  float4 a = *(const float4*)(src);
  float4 b = *(const float4*)(src + 4);
  uint4 o;
  o.x = pk_bf16(a.x, a.y); o.y = pk_bf16(a.z, a.w);
  o.z = pk_bf16(b.x, b.y); o.w = pk_bf16(b.z, b.w);
  *(uint4*)(qb + (size_t)row * D_ + lane * 8) = o;
  float ss = a.x*a.x + a.y*a.y + a.z*a.z + a.w*a.w
           + b.x*b.x + b.y*b.y + b.z*b.z + b.w*b.w;
#pragma unroll
  for (int off = 32; off; off >>= 1) ss += __shfl_xor(ss, off);
  if (lane == 0) qn[row] = sqrtf(ss);
  if (row == 0)
    for (int i = lane; i < B_ * C_; i += 64) counts[i] = 0;
}

// ---- fused GEMM: score = (q . t) * rsqrt(||t||^2); deterministic-slot candidate append ----
// BM=256 (all queries), BN=64, BK=64; 4 waves (2m x 2n); 256 threads; train read once.
__global__ __launch_bounds__(256) void k_gemm(const float* __restrict__ tf,
                                              const u16* __restrict__ qb,
                                              const float* __restrict__ qn,
                                              uint2* __restrict__ slots,
                                              uint2* __restrict__ ovf,
                                              unsigned* __restrict__ ovfCnt) {
  __shared__ __align__(16) u16 As[256 * 64];   // 32 KB, XOR-swizzled
  __shared__ __align__(16) u16 Bs[BN_ * 64];   //  8 KB, XOR-swizzled
  __shared__ float rnS[BN_];
  __shared__ float tauS[B_];
  __shared__ int   lcnt[B_];                   // per-query block-local slot counter
  const int tid   = threadIdx.x;               // 0..255
  const int layer = blockIdx.y;
  const int bx    = blockIdx.x;
  const int n0    = bx * BN_;
  const int lane  = tid & 63, wave = tid >> 6; // 4 waves
  const int wr    = wave >> 1, wc = wave & 1;  // 2 M-halves x 2 N-halves
  const int kg    = lane >> 4, rl = lane & 15;

  const u16*   qbase = qb + (size_t)layer * B_ * D_;
  const float* tbase = tf + (size_t)layer * N_ * D_;

  tauS[tid] = qn[layer * B_ + tid] * (TAUZ / 22.627416997969522f);
  lcnt[tid] = 0;

  // A staging: 8 chunks/thread; chunk j -> row = j*32 + (tid>>3), c16 = tid&7
  const int arow0 = tid >> 3, ac16 = tid & 7;
  // B staging: 4 chunks/thread; chunk j -> row = j*16 + (tid>>4), c16 = tid&15
  const int brow0 = tid >> 4, bc16 = tid & 15;

  float ssj[4] = {0.f, 0.f, 0.f, 0.f};
  f32x4 acc[8][2];
  const f32x4 vz = {0.f, 0.f, 0.f, 0.f};
#pragma unroll
  for (int i = 0; i < 8; ++i) { acc[i][0] = vz; acc[i][1] = vz; }

  for (int kt = 0; kt < 8; ++kt) {
    // B global loads (fp32), coalesced: 4 rows x 256B contiguous per wave-instr
    float4 bf[4];
#pragma unroll
    for (int j = 0; j < 4; ++j) {
      int row = j * 16 + brow0;
      int n = n0 + row; n = n < N_ ? n : N_ - 1;
      bf[j] = *(const float4*)(tbase + (size_t)n * D_ + kt * 64 + bc16 * 4);
    }
    __syncthreads();   // previous tile fully consumed
    // A stage: 8 rows x 128B contiguous per wave-instr; swizzled ds_write_b128
#pragma unroll
    for (int j = 0; j < 8; ++j) {
      const int row = j * 32 + arow0;
      uint4 v = *(const uint4*)(qbase + (size_t)row * D_ + kt * 64 + ac16 * 8);
      *(uint4*)((char*)As + row * 128 + ((ac16 ^ (row & 7)) << 4)) = v;
    }
    // B stage: convert + swizzled ds_write_b64, accumulate ||t||^2 per chunk-row
#pragma unroll
    for (int j = 0; j < 4; ++j) {
      const int row = j * 16 + brow0;
      const float4 f = bf[j];
      ssj[j] += f.x*f.x + f.y*f.y + f.z*f.z + f.w*f.w;
      uint2 o;
      o.x = pk_bf16(f.x, f.y);
      o.y = pk_bf16(f.z, f.w);
      *(uint2*)((char*)Bs + row * 128 + ((((bc16 >> 1)) ^ (row & 7)) << 4) + (bc16 & 1) * 8) = o;
    }
    __syncthreads();   // tile ready
#pragma unroll
    for (int ks = 0; ks < 2; ++ks) {
      const int g = ks * 4 + kg;               // 8-elem k-granule index
      short8 bfr[2];
#pragma unroll
      for (int nf = 0; nf < 2; ++nf) {
        const int r = wc * 32 + nf * 16 + rl;
        bfr[nf] = *(const short8*)((const char*)Bs + r * 128 + ((g ^ (r & 7)) << 4));
      }
#pragma unroll
      for (int mf = 0; mf < 8; ++mf) {
        const int m = wr * 128 + mf * 16 + rl;
        const short8 a = *(const short8*)((const char*)As + m * 128 + ((g ^ (m & 7)) << 4));
        acc[mf][0] = __builtin_amdgcn_mfma_f32_16x16x32_bf16(a, bfr[0], acc[mf][0], 0, 0, 0);
        acc[mf][1] = __builtin_amdgcn_mfma_f32_16x16x32_bf16(a, bfr[1], acc[mf][1], 0, 0, 0);
      }
    }
  }
  // full-row 1/||t||: reduce ssj within 16-lane chunk groups
#pragma unroll
  for (int j = 0; j < 4; ++j) {
    float s = ssj[j];
    s += __shfl_xor(s, 1);
    s += __shfl_xor(s, 2);
    s += __shfl_xor(s, 4);
    s += __shfl_xor(s, 8);
    if ((lane & 15) == 0) rnS[j * 16 + wave * 4 + (lane >> 4)] = 1.0f / sqrtf(s);
  }
  __syncthreads();

  // epilogue: deterministic slot append, NO contended global atomics
  const int crow = (lane >> 4) * 4;
  uint2* slotL = slots + (size_t)layer * B_ * NBX_ * SLOTS_;
#pragma unroll
  for (int nf = 0; nf < 2; ++nf) {
    const int cidx = wc * 32 + nf * 16 + rl;
    const int n = n0 + cidx;
    if (n < N_) {
      const float rn = rnS[cidx];
#pragma unroll
      for (int mf = 0; mf < 8; ++mf) {
        const int bq0 = wr * 128 + mf * 16 + crow;
#pragma unroll
        for (int j = 0; j < 4; ++j) {
          const float s = acc[mf][nf][j] * rn;
          const int bq = bq0 + j;
          if (s >= tauS[bq]) {
            const int pos = atomicAdd(&lcnt[bq], 1);   // LDS atomic: cheap
            if (pos < SLOTS_) {
              slotL[((size_t)bq * NBX_ + bx) * SLOTS_ + pos] =
                  make_uint2(__float_as_uint(s), (unsigned)n);
            } else {                                    // rare (~2e-4/cell)
              const unsigned op = atomicAdd(ovfCnt, 1u);
              if (op < OVF_CAP)
                ovf[op] = make_uint2(__float_as_uint(s),
                                     ((unsigned)layer << 25) | ((unsigned)bq << 17) | (unsigned)n);
            }
          }
        }
      }
    }
  }
}

// ---- per-(layer,query): gather candidates -> rank-75 -> fp64 rescore -> exact rank ----
__global__ __launch_bounds__(256) void k_select(const uint2* __restrict__ slots,
                                                const uint2* __restrict__ ovf,
                                                const unsigned* __restrict__ ovfCnt,
                                                const float* __restrict__ tf,
                                                const float* __restrict__ qf,
                                                const int* __restrict__ labels,
                                                int* __restrict__ counts) {
  __shared__ float  sVal[CAP_];
  __shared__ int    sIdx[CAP_];
  __shared__ int    rIdxN[RCAP_];
  __shared__ double rVal[RCAP_];
  __shared__ unsigned s75u;
  __shared__ int nC, nRs;
  const int tid   = threadIdx.x;
  const int lane  = tid & 63;
  const int b     = blockIdx.x;
  const int layer = blockIdx.y;
  if (tid == 0) { nC = 0; nRs = 0; s75u = 0u; }
  __syncthreads();

  // gather from this query's contiguous slot strip (wave-ballot aggregated append)
  const uint2* sl = slots + ((size_t)layer * B_ + b) * NBX_ * SLOTS_;
  const int nSlots = NBX_ * SLOTS_;                 // 6252
  const int iters = (nSlots + 255) / 256;
  for (int it = 0; it < iters; ++it) {
    const int i = it * 256 + tid;
    float v = 0.f; unsigned nn = 0;
    if (i < nSlots) { uint2 e = sl[i]; v = __uint_as_float(e.x); nn = e.y; }
    const bool pred = (v > 0.f);
    const unsigned long long mk = __ballot(pred);
    if (mk) {
      int base = 0;
      if (lane == 0) base = atomicAdd(&nC, __popcll(mk));
      base = __shfl(base, 0);
      if (pred) {
        const int p = base + __popcll(mk & ((1ull << lane) - 1ull));
        if (p < CAP_) { sVal[p] = v; sIdx[p] = (int)nn; }
      }
    }
  }
  // overflow list (tiny, shared by all blocks)
  const int oc = min((int)*ovfCnt, OVF_CAP);
  for (int i = tid; i < oc; i += 256) {
    uint2 e = ovf[i];
    if ((int)(e.y >> 25) == layer && (int)((e.y >> 17) & 0xFFu) == b) {
      const int p = atomicAdd(&nC, 1);
      if (p < CAP_) { sVal[p] = __uint_as_float(e.x); sIdx[p] = (int)(e.y & 0x1FFFFu); }
    }
  }
  __syncthreads();
  const int m = min(nC, CAP_);

  // exact 75th-largest approx score (total order: value desc, idx asc)
  if (m > K_) {
    for (int c = tid; c < m; c += 256) {
      const float vc = sVal[c];
      const int   ic = sIdx[c];
      int r = 0;
      for (int j = 0; j < m; ++j) {
        const float vj = sVal[j];
        r += (vj > vc) || (vj == vc && sIdx[j] < ic);
      }
      if (r == K_ - 1) s75u = __float_as_uint(vc);   // unique writer
    }
  }
  __syncthreads();
  const float tr = (m > K_) ? (__uint_as_float(s75u) - MARGIN) : -1e30f;
  for (int c = tid; c < m; c += 256) {
    if (sVal[c] >= tr) {
      const int p = atomicAdd(&nRs, 1);
      if (p < RCAP_) rIdxN[p] = sIdx[c];
    }
  }
  __syncthreads();
  const int R = min(nRs, RCAP_);

  // exact fp64 rescore: one wave per candidate row
  const int wave = tid >> 6;
  const float* q     = qf + ((size_t)layer * B_ + b) * D_;
  const float* tbase = tf + (size_t)layer * N_ * D_;
  const float4 qa = *(const float4*)(q + lane * 8);
  const float4 qc = *(const float4*)(q + lane * 8 + 4);
  for (int c = wave; c < R; c += 4) {
    const float* t = tbase + (size_t)rIdxN[c] * D_ + lane * 8;
    const float4 ta = *(const float4*)t;
    const float4 tc = *(const float4*)(t + 4);
    double dot = (double)qa.x * ta.x + (double)qa.y * ta.y
               + (double)qa.z * ta.z + (double)qa.w * ta.w
               + (double)qc.x * tc.x + (double)qc.y * tc.y
               + (double)qc.z * tc.z + (double)qc.w * tc.w;
    double sq  = (double)ta.x * ta.x + (double)ta.y * ta.y
               + (double)ta.z * ta.z + (double)ta.w * ta.w
               + (double)tc.x * tc.x + (double)tc.y * tc.y
               + (double)tc.z * tc.z + (double)tc.w * tc.w;
#pragma unroll
    for (int off = 32; off; off >>= 1) {
      dot += __shfl_xor(dot, off);
      sq  += __shfl_xor(sq, off);
    }
    if (lane == 0) rVal[c] = dot / sqrt(sq);
  }
  __syncthreads();

  // exact rank among rescored set (contains all true top-75)
  for (int c = tid; c < R; c += 256) {
    const double vc = rVal[c];
    const int    ic = rIdxN[c];
    int r = 0;
    for (int j = 0; j < R; ++j) {
      const double vj = rVal[j];
      r += (vj > vc) || (vj == vc && rIdxN[j] < ic);
    }
    if (r < K_) atomicAdd(&counts[b * C_ + labels[ic]], 1);
  }
}

// ---- conformal p-values + credibility ----
__global__ __launch_bounds__(1024) void k_final(const int* __restrict__ counts,
                                                const int* __restrict__ cali,
                                                float* __restrict__ out) {
  __shared__ int   cal[NCALI_];
  __shared__ float pv[B_ * C_];
  const int tid = threadIdx.x;
  for (int i = tid; i < NCALI_; i += 1024) cal[i] = cali[i];
  __syncthreads();
  for (int t = tid; t < B_ * C_; t += 1024) {
    const int val = L_ * K_ - counts[t];
    int cntv = 0;
    for (int i = 0; i < NCALI_; ++i) cntv += (cal[i] >= val) ? 1 : 0;
    pv[t] = (float)cntv / (float)NCALI_;
  }
  __syncthreads();
  for (int b = tid; b < B_; b += 1024) {
    float best = pv[b * C_];
    int bc = 0;
#pragma unroll
    for (int c = 1; c < C_; ++c) {
      const float p = pv[b * C_ + c];
      if (p > best) { best = p; bc = c; }
    }
#pragma unroll
    for (int c = 0; c < C_; ++c) out[b * C_ + c] = (c == bc) ? best : 0.f;
  }
}

extern "C" void kernel_launch(void* const* d_in, const int* in_sizes, int n_in,
                              void* d_out, int out_size, void* d_ws, size_t ws_size,
                              hipStream_t stream) {
  (void)in_sizes; (void)n_in; (void)out_size;
  const float* train  = (const float*)d_in[0];
  const float* query  = (const float*)d_in[1];
  const int*   labels = (const int*)d_in[2];
  const int*   cali   = (const int*)d_in[3];
  float* out = (float*)d_out;

  char* ws = (char*)d_ws;
  u16*      qb     = (u16*)     (ws);            //    524,288 B [L*B*D bf16]
  float*    qn     = (float*)   (ws + 524288);   //      2,048 B [L*B]
  int*      counts = (int*)     (ws + 526336);   //     10,240 B [B*C]
  unsigned* ovfCnt = (unsigned*)(ws + 536576);   //        256 B
  uint2*    ovf    = (uint2*)   (ws + 536832);   //    524,288 B [OVF_CAP]
  uint2*    slots  = (uint2*)   (ws + 1061120);  // 25,608,192 B [L*B*NBX_*SLOTS_]
  if (ws_size < 52534528u) return;

  const long slot16 = 25608192 / 16;
  k_zero<<<dim3(2048), dim3(256), 0, stream>>>((uint4*)slots, slot16, ovfCnt);
  k_qprep<<<dim3(L_ * B_), dim3(64), 0, stream>>>(query, qb, qn, counts);
  k_gemm<<<dim3(NBX_, L_), dim3(256), 0, stream>>>(train, qb, qn, slots, ovf, ovfCnt);
  k_select<<<dim3(B_, L_), dim3(256), 0, stream>>>(slots, ovf, ovfCnt, train, query, labels, counts);
  k_final<<<dim3(1), dim3(1024), 0, stream>>>(counts, cali, out);
}